// Round 8
// baseline (263.459 us; speedup 1.0000x reference)
//
#include <hip/hip_runtime.h>
#include <math.h>

#define NN 5000
#define NE 80000
#define EPSB 1e-3f
#define GZ 100   // gram k-slices (50 rows each)

// bf16 helpers (RNE pack / unpack)
__device__ __forceinline__ unsigned int f2bf(float f) {
    unsigned int u = __float_as_uint(f);
    return (u + 0x7FFFu + ((u >> 16) & 1u)) >> 16;
}
__device__ __forceinline__ float bf2f(unsigned short h) {
    return __uint_as_float(((unsigned int)h) << 16);
}

// ------------------------------------------- prep: pad x + degree count ----

__global__ void k_prep(const float* __restrict__ x, float* __restrict__ x_p,
                       const int* __restrict__ ei, int* __restrict__ counts) {
    int t = blockIdx.x * 256 + threadIdx.x;
    if (t < NN * 36) {
        int n = t / 36, i = t - n * 36;
        x_p[t] = (i < 35) ? x[n * 35 + i] : 0.f;
    }
    if (t < NE) atomicAdd(&counts[ei[NE + t]], 1);
}

__global__ void k_scan(const int* __restrict__ counts, int* __restrict__ offs) {
    __shared__ int ps[256];
    int t = threadIdx.x;
    int base = t * 20;
    int loc[20];
    int s = 0;
#pragma unroll
    for (int j = 0; j < 20; ++j) {
        int idx = base + j;
        int v = (idx < NN) ? counts[idx] : 0;
        loc[j] = s; s += v;
    }
    ps[t] = s;
    __syncthreads();
    for (int off = 1; off < 256; off <<= 1) {
        int v = (t >= off) ? ps[t - off] : 0;
        __syncthreads();
        ps[t] += v;
        __syncthreads();
    }
    int pre = (t > 0) ? ps[t - 1] : 0;
#pragma unroll
    for (int j = 0; j < 20; ++j) {
        int idx = base + j;
        if (idx < NN) offs[idx] = pre + loc[j];
    }
    if (t == 255) offs[NN] = ps[255];
}

// --------------------- layer 1 phase 1: per-edge messages (+ slot alloc) ---
// W1/b1 read directly with wave-uniform, compile-time-offset addresses ->
// compiler emits s_load (SGPR broadcast); zero LDS traffic in the hot loop.

__global__ __launch_bounds__(256) void k_edge1(
    const int* __restrict__ ei, const float* __restrict__ ea,
    const int* __restrict__ offs, int* __restrict__ cursor,
    int* __restrict__ eslot,
    const float* __restrict__ x_p,
    const float* __restrict__ W1, const float* __restrict__ b1,
    unsigned short* __restrict__ msg1)
{
    int e = blockIdx.x * 256 + threadIdx.x;
    if (e >= NE) return;
    int dst = ei[NE + e];
    int p = atomicAdd(&cursor[dst], 1);
    int slot = offs[dst] + p;
    eslot[e] = slot;

    int src = ei[e];
    float a = ea[e];
    const float4* xp4 = (const float4*)(x_p + src * 36);
    float acc[36];
#pragma unroll
    for (int o = 0; o < 36; ++o) acc[o] = 0.f;
#pragma unroll
    for (int q = 0; q < 9; ++q) {
        float4 xv = xp4[q];
        float xs4[4] = {xv.x, xv.y, xv.z, xv.w};
#pragma unroll
        for (int r = 0; r < 4; ++r) {
            int i = q * 4 + r;
            if (i >= 35) continue;          // compile-time elided
            float xi = xs4[r];
            const float* wr = W1 + i * 35;  // wave-uniform -> s_load
            const float* br = b1 + i * 35;
#pragma unroll
            for (int o = 0; o < 35; ++o)
                acc[o] = fmaf(xi, fmaxf(0.f, fmaf(a, wr[o], br[o])), acc[o]);
        }
    }
    acc[35] = 0.f;
    unsigned int pk[18];
#pragma unroll
    for (int k = 0; k < 18; ++k)
        pk[k] = f2bf(acc[2 * k]) | (f2bf(acc[2 * k + 1]) << 16);
    uint2* dstp = (uint2*)(msg1 + (size_t)slot * 36);
#pragma unroll
    for (int j = 0; j < 9; ++j) dstp[j] = make_uint2(pk[2 * j], pk[2 * j + 1]);
}

// ----------------------------------- layer 1 phase 2: gather + finalize ----

__global__ __launch_bounds__(256) void k_sum1(
    const int* __restrict__ offs,
    const unsigned short* __restrict__ msg1,
    const float* __restrict__ x_p,
    const float* __restrict__ root1, const float* __restrict__ bias1,
    const float* __restrict__ g, const float* __restrict__ be,
    const float* __restrict__ rm, const float* __restrict__ rv,
    float* __restrict__ x1p)
{
    int t = blockIdx.x * 256 + threadIdx.x;
    if (t >= NN * 36) return;
    int n = t / 36, o = t - n * 36;
    if (o == 35) { x1p[t] = 0.f; return; }
    int off = offs[n];
    int deg = offs[n + 1] - off;
    const unsigned short* base = msg1 + (size_t)off * 36 + o;
    float s = 0.f;
    for (int j = 0; j < deg; ++j) s += bf2f(base[(size_t)j * 36]);
    float mean = s / fmaxf((float)deg, 1.0f);
    float r = 0.f;
#pragma unroll 7
    for (int i = 0; i < 35; ++i) r = fmaf(x_p[n * 36 + i], root1[i * 35 + o], r);
    float h = mean + r + bias1[o];
    float z = (h - rm[o]) * (g[o] * rsqrtf(rv[o] + EPSB)) + be[o];
    x1p[t] = 1.f / (1.f + expf(-z));
}

// ------------------------------------- layer 3 phase 1: per-edge messages --
// thread = one edge x 32-output chunk (gridDim.y = 5). msg layout [5][slot][32].
// W3/b3 via wave-uniform scalar loads; no LDS.

__global__ __launch_bounds__(256) void k_edge3(
    const int* __restrict__ ei, const float* __restrict__ ea,
    const int* __restrict__ eslot,
    const float* __restrict__ x1p,
    const float* __restrict__ W3, const float* __restrict__ b3,
    unsigned short* __restrict__ msg3)
{
    int e = blockIdx.x * 256 + threadIdx.x;
    if (e >= NE) return;
    const float* Wb = W3 + blockIdx.y * 32;   // uniform base
    const float* Bb = b3 + blockIdx.y * 32;
    int src = ei[e];
    float a = ea[e];
    const float4* xp4 = (const float4*)(x1p + src * 36);
    float acc[32];
#pragma unroll
    for (int o = 0; o < 32; ++o) acc[o] = 0.f;
#pragma unroll
    for (int q = 0; q < 9; ++q) {
        float4 xv = xp4[q];
        float xs4[4] = {xv.x, xv.y, xv.z, xv.w};
#pragma unroll
        for (int r = 0; r < 4; ++r) {
            int i = q * 4 + r;
            if (i >= 35) continue;           // compile-time elided
            float xi = xs4[r];
            const float* wr = Wb + i * 160;  // wave-uniform -> s_load
            const float* br = Bb + i * 160;
#pragma unroll
            for (int o = 0; o < 32; ++o)
                acc[o] = fmaf(xi, fmaxf(0.f, fmaf(a, wr[o], br[o])), acc[o]);
        }
    }
    unsigned int pk[16];
#pragma unroll
    for (int k = 0; k < 16; ++k)
        pk[k] = f2bf(acc[2 * k]) | (f2bf(acc[2 * k + 1]) << 16);
    uint4* dst = (uint4*)(msg3 + ((size_t)blockIdx.y * NE + eslot[e]) * 32);
#pragma unroll
    for (int j = 0; j < 4; ++j)
        dst[j] = make_uint4(pk[4 * j], pk[4 * j + 1], pk[4 * j + 2], pk[4 * j + 3]);
}

// ----------------------------------- layer 3 phase 2: gather + finalize ----
// block 320 = 4 nodes x 80 lanes; each lane 2 adjacent outputs (one uint load/row)

__global__ __launch_bounds__(320) void k_sum3(
    const int* __restrict__ offs,
    const unsigned short* __restrict__ msg3,
    const float* __restrict__ x1p,
    const float* __restrict__ root3, const float* __restrict__ bias3,
    const float* __restrict__ g, const float* __restrict__ be,
    const float* __restrict__ rm, const float* __restrict__ rv,
    float* __restrict__ x3)
{
    __shared__ float xn[4][36];
    int tid = threadIdx.x;
    int g_ = tid / 80;
    int o2 = tid - g_ * 80;
    int o  = o2 * 2;
    int n  = blockIdx.x * 4 + g_;
    if (tid < 144) xn[tid / 36][tid % 36] = x1p[(blockIdx.x * 4 + tid / 36) * 36 + tid % 36];
    __syncthreads();
    int off = offs[n];
    int deg = offs[n + 1] - off;
    int chunk = o >> 5, oo = o & 31;
    const unsigned short* base = msg3 + ((size_t)chunk * NE + off) * 32 + oo;
    float s0 = 0.f, s1 = 0.f;
    for (int j = 0; j < deg; ++j) {
        unsigned int u = *(const unsigned int*)(base + (size_t)j * 32);
        s0 += bf2f((unsigned short)(u & 0xffff));
        s1 += bf2f((unsigned short)(u >> 16));
    }
    float inv = 1.f / fmaxf((float)deg, 1.0f);
    float m0 = s0 * inv, m1 = s1 * inv;
    float r0 = 0.f, r1 = 0.f;
#pragma unroll 7
    for (int i = 0; i < 35; ++i) {
        float xvi = xn[g_][i];
        r0 = fmaf(xvi, root3[i * 160 + o], r0);
        r1 = fmaf(xvi, root3[i * 160 + o + 1], r1);
    }
    float h0 = m0 + r0 + bias3[o];
    float h1 = m1 + r1 + bias3[o + 1];
    float z0 = (h0 - rm[o]) * (g[o] * rsqrtf(rv[o] + EPSB)) + be[o];
    float z1 = (h1 - rm[o + 1]) * (g[o + 1] * rsqrtf(rv[o + 1] + EPSB)) + be[o + 1];
    float2 res = make_float2(1.f / (1.f + expf(-z0)), 1.f / (1.f + expf(-z1)));
    *(float2*)(x3 + n * 160 + o) = res;
}

// ----------------------------------------------------------- gram ----------
// grid (3,3,GZ) k-chunk 50; unrolled for load ILP

__global__ void k_gram(const float* __restrict__ x3, float* __restrict__ part) {
    int tx = threadIdx.x, ty = threadIdx.y;
    int i = blockIdx.x * 64 + tx * 4;
    int j = blockIdx.y * 64 + ty * 4;
    if (i >= 160 || j >= 160) return;
    int k0 = blockIdx.z * 50;
    float acc[4][4];
#pragma unroll
    for (int r = 0; r < 4; ++r)
#pragma unroll
        for (int c = 0; c < 4; ++c) acc[r][c] = 0.f;
#pragma unroll 5
    for (int k = k0; k < k0 + 50; ++k) {
        float4 av = *(const float4*)&x3[k * 160 + i];
        float4 bv = *(const float4*)&x3[k * 160 + j];
        float ar[4] = {av.x, av.y, av.z, av.w};
        float br[4] = {bv.x, bv.y, bv.z, bv.w};
#pragma unroll
        for (int r = 0; r < 4; ++r)
#pragma unroll
            for (int c = 0; c < 4; ++c) acc[r][c] = fmaf(ar[r], br[c], acc[r][c]);
    }
    float* pp = part + (size_t)blockIdx.z * 25600;
#pragma unroll
    for (int r = 0; r < 4; ++r)
#pragma unroll
        for (int c = 0; c < 4; ++c) pp[(i + r) * 160 + (j + c)] = acc[r][c];
}

__global__ void k_reduce(const float* __restrict__ part, float* __restrict__ out) {
    int t = blockIdx.x * 256 + threadIdx.x;
    if (t >= 25600) return;
    float s = 0.f;
#pragma unroll 10
    for (int z = 0; z < GZ; ++z) s += part[(size_t)z * 25600 + t];
    out[t] = s;
}

// ----------------------------------------------------------------- launch --

extern "C" void kernel_launch(void* const* d_in, const int* in_sizes, int n_in,
                              void* d_out, int out_size, void* d_ws, size_t ws_size,
                              hipStream_t stream) {
    const float* x     = (const float*)d_in[0];
    const int*   ei    = (const int*)d_in[1];
    const float* ea    = (const float*)d_in[2];
    const float* W1    = (const float*)d_in[3];
    const float* b1    = (const float*)d_in[4];
    const float* root1 = (const float*)d_in[5];
    const float* bias1 = (const float*)d_in[6];
    const float* g1    = (const float*)d_in[7];
    const float* be1   = (const float*)d_in[8];
    const float* rm1   = (const float*)d_in[9];
    const float* rv1   = (const float*)d_in[10];
    const float* W3    = (const float*)d_in[11];
    const float* b3    = (const float*)d_in[12];
    const float* root3 = (const float*)d_in[13];
    const float* bias3 = (const float*)d_in[14];
    const float* g3    = (const float*)d_in[15];
    const float* be3   = (const float*)d_in[16];
    const float* rm3   = (const float*)d_in[17];
    const float* rv3   = (const float*)d_in[18];
    float* out = (float*)d_out;

    // ---- workspace layout (byte offsets, all 16B-aligned) ----
    char* wsb = (char*)d_ws;
    int*   counts = (int*)(wsb + 0);                    //  20480 B
    int*   cursor = (int*)(wsb + 20480);                //  20480 B
    int*   offs   = (int*)(wsb + 40960);                //  20480 B
    int*   eslot  = (int*)(wsb + 61440);                // 320512 B -> end 381952
    float* x_p    = (float*)(wsb + 381952);             // 720000 B -> end 1101952
    float* x1p    = (float*)(wsb + 1101952);            // 720000 B -> end 1821952
    float* x3     = (float*)(wsb + 1821952);            // 3.2 MB  -> end 5021952
    unsigned short* msg1 = (unsigned short*)(wsb + 5021952);  // 5.76 MB -> end 10781952
    unsigned short* msg3 = (unsigned short*)(wsb + 10781952); // 25.6 MB -> end 36381952
    float* part   = (float*)(wsb + 10781952);           // 10.24 MB, aliases msg3 (dead)

    hipMemsetAsync(d_ws, 0, (size_t)2 * 5120 * sizeof(int), stream);  // counts+cursor

    int eb = (NE + 255) / 256;
    k_prep <<<(NN * 36 + 255) / 256, 256, 0, stream>>>(x, x_p, ei, counts);
    k_scan <<<1, 256, 0, stream>>>(counts, offs);
    k_edge1<<<eb, 256, 0, stream>>>(ei, ea, offs, cursor, eslot, x_p, W1, b1, msg1);
    k_sum1 <<<(NN * 36 + 255) / 256, 256, 0, stream>>>(offs, msg1, x_p,
                                                       root1, bias1, g1, be1, rm1, rv1, x1p);
    k_edge3<<<dim3(eb, 5), 256, 0, stream>>>(ei, ea, eslot, x1p, W3, b3, msg3);
    k_sum3 <<<1250, 320, 0, stream>>>(offs, msg3, x1p,
                                      root3, bias3, g3, be3, rm3, rv3, x3);
    k_gram <<<dim3(3, 3, GZ), dim3(16, 16), 0, stream>>>(x3, part);
    k_reduce<<<(25600 + 255) / 256, 256, 0, stream>>>(part, out);
}